// Round 9
// baseline (6577.348 us; speedup 1.0000x reference)
//
#include <hip/hip_runtime.h>

#define NX 128
#define NSTEPS 4096

typedef float f2 __attribute__((ext_vector_type(2)));
typedef float f4 __attribute__((ext_vector_type(4)));

union F4 {
  f4 v;
  f2 h[2];
  float s[4];
};

// packed fp32 FMA: d = a*b + d on both 32-bit halves (full-rate on CDNA)
__device__ __forceinline__ void pk_fma(f2& d, f2 a, f2 b) {
  asm("v_pk_fma_f32 %0, %1, %2, %0" : "+v"(d) : "v"(a), "v"(b));
}

// v + DPP-moved v (quad_perm xor1)
template <int CTRL>
__device__ __forceinline__ float dpp_add_f(float v) {
  int i = __float_as_int(v);
  int s = __builtin_amdgcn_update_dpp(i, i, CTRL, 0xf, 0xf, false);
  return v + __int_as_float(s);
}

// SINGLE WAVE: producer == consumer, so the per-step cross-wave
// ds_write -> lgkmcnt -> s_barrier -> ds_read chain (~400 cyc in the 4-wave
// version) collapses to the in-order DS pipe: write then read, no barrier.
__launch_bounds__(64, 1)
__global__ void nmpc_rollout_kernel(const float* __restrict__ x0,
                                    const float* __restrict__ xref,
                                    const float* __restrict__ useq,
                                    const float* __restrict__ A,
                                    const float* __restrict__ B,
                                    float* __restrict__ out) {
  // x stored as 2 slices of 64 floats at 68-word stride: the two broadcast
  // addresses per ds_read_b128 (words 4q vs 68+4q) hit disjoint bank quads.
  __shared__ __align__(16) float xs0[136];
  __shared__ __align__(16) float xs1[136];
  __shared__ float2 us[NSTEPS];  // interleaved (u0[s], u1[s]) pairs, 32KB

  const int l = threadIdx.x;   // 0..63
  const int g = l >> 1;        // row-group 0..31 (4 rows each)
  const int p = l & 1;         // column half 0..1 (64 cols each)
  const int r0 = 4 * g + 2 * p;  // this lane finalizes rows r0, r0+1

  // ---- one-time staging of useq into LDS (interleaved pairs) ----
#pragma unroll
  for (int k = 0; k < NSTEPS / 64; ++k) {
    int idx = k * 64 + l;
    us[idx] = make_float2(useq[idx], useq[NSTEPS + idx]);
  }

  // ---- A fragment: rows 4g..4g+3, cols 64p..64p+63, prescaled by 2*log2(e)
  // so the dot product feeds exp2 directly. 256 VGPRs (1 wave/SIMD). ----
  const float K = 2.8853900817779268f;
  F4 a0[16], a1[16], a2[16], a3[16];
#pragma unroll
  for (int q = 0; q < 16; ++q) {
    a0[q].v = *(const f4*)(A + (4 * g + 0) * NX + 64 * p + 4 * q) * K;
    a1[q].v = *(const f4*)(A + (4 * g + 1) * NX + 64 * p + 4 * q) * K;
    a2[q].v = *(const f4*)(A + (4 * g + 2) * NX + 64 * p + 4 * q) * K;
    a3[q].v = *(const f4*)(A + (4 * g + 3) * NX + 64 * p + 4 * q) * K;
  }
  const float b00 = B[2 * r0] * K, b01 = B[2 * r0 + 1] * K;
  const float b10 = B[2 * r0 + 2] * K, b11 = B[2 * r0 + 3] * K;

  // fp64 master state for this lane's two rows; xf* = f32 matvec image.
  double xc0 = (double)x0[r0], xc1 = (double)x0[r0 + 1];
  float xf0 = (float)xc0, xf1 = (float)xc1;
  double mse;
  {
    double d0 = xc0 - (double)xref[r0];
    double d1 = xc1 - (double)xref[r0 + 1];
    mse = d0 * d0 + d1 * d1;
  }
  *(float2*)(xs0 + 68 * (r0 >> 6) + (r0 & 63)) = make_float2(xf0, xf1);

  // ---- 4-deep rolling prefetch of xref row-pairs (off the x-chain) ----
  float2 xr0 = *(const float2*)(xref + 1 * NX + r0);
  float2 xr1 = *(const float2*)(xref + 2 * NX + r0);
  float2 xr2 = *(const float2*)(xref + 3 * NX + r0);
  float2 xr3 = *(const float2*)(xref + 4 * NX + r0);

  auto step = [&](const float* __restrict__ src, float* __restrict__ dst, int s) {
    float2 uv = us[s];  // broadcast; consumed off-chain
    int nref = (s + 5 <= NSTEPS) ? (s + 5) : NSTEPS;
    float2 xnew = *(const float2*)(xref + nref * NX + r0);

    // ---- 16x ds_read_b128 (2 bcast addrs, conflict-free) fused with
    //      128 pk_fma in 8 independent chains (depth 16) ----
    const f4* xb = (const f4*)(src + 68 * p);
    f2 ae0 = (f2)(0.f), ao0 = (f2)(0.f), ae1 = (f2)(0.f), ao1 = (f2)(0.f);
    f2 ae2 = (f2)(0.f), ao2 = (f2)(0.f), ae3 = (f2)(0.f), ao3 = (f2)(0.f);
#pragma unroll
    for (int q = 0; q < 16; ++q) {
      F4 xv;
      xv.v = xb[q];
      pk_fma(ae0, a0[q].h[0], xv.h[0]);
      pk_fma(ao0, a0[q].h[1], xv.h[1]);
      pk_fma(ae1, a1[q].h[0], xv.h[0]);
      pk_fma(ao1, a1[q].h[1], xv.h[1]);
      pk_fma(ae2, a2[q].h[0], xv.h[0]);
      pk_fma(ao2, a2[q].h[1], xv.h[1]);
      pk_fma(ae3, a3[q].h[0], xv.h[0]);
      pk_fma(ao3, a3[q].h[1], xv.h[1]);
    }
    float bu0 = fmaf(b01, uv.y, b00 * uv.x);  // off critical path
    float bu1 = fmaf(b11, uv.y, b10 * uv.x);

    f2 h0 = ae0 + ao0, h1 = ae1 + ao1, h2 = ae2 + ao2, h3 = ae3 + ao3;
    float acc0 = h0.x + h0.y;
    float acc1 = h1.x + h1.y;
    float acc2 = h2.x + h2.y;
    float acc3 = h3.x + h3.y;

    // single-stage reduce: pair lanes exchange half-sums (VALU pipe)
    acc0 = dpp_add_f<0xB1>(acc0);  // quad_perm [1,0,3,2]: xor1
    acc1 = dpp_add_f<0xB1>(acc1);
    acc2 = dpp_add_f<0xB1>(acc2);
    acc3 = dpp_add_f<0xB1>(acc3);

    // lane p takes rows 4g+2p, 4g+2p+1
    float s0 = p ? acc2 : acc0;
    float s1 = p ? acc3 : acc1;

    // tanh(z) = 1 - 2/(exp2(zk)+1) with zk pre-scaled; saturates to +-1
    float z0 = s0 + bu0;
    float z1 = s1 + bu1;
    float e0 = __builtin_amdgcn_exp2f(z0);
    float e1 = __builtin_amdgcn_exp2f(z1);
    float xd0 = fmaf(-2.f, __builtin_amdgcn_rcpf(e0 + 1.f), 1.f);
    float xd1 = fmaf(-2.f, __builtin_amdgcn_rcpf(e1 + 1.f), 1.f);
    float nf0 = xf0 + xd0;  // f32 anchor: short store chain
    float nf1 = xf1 + xd1;
    *(float2*)(dst + 68 * (r0 >> 6) + (r0 & 63)) = make_float2(nf0, nf1);
    // same-wave DS pipe is in-order: next step's ds_read sees this write
    // without any barrier or explicit waitcnt.

    xc0 += (double)xd0;  // off-chain f64 master state
    xc1 += (double)xd1;
    xf0 = (float)xc0;    // re-anchor (off-chain)
    xf1 = (float)xc1;
    double d0 = xc0 - (double)xr0.x;  // pair loaded 4 steps ago
    double d1 = xc1 - (double)xr0.y;
    mse = fma(d0, d0, mse);
    mse = fma(d1, d1, mse);

    xr0 = xr1; xr1 = xr2; xr2 = xr3; xr3 = xnew;  // SSA-renamed by unroll
  };

#pragma unroll 1
  for (int s = 0; s < NSTEPS; s += 2) {
    step(xs0, xs1, s);
    step(xs1, xs0, s + 1);
  }

  // ---- final reduction (each row counted exactly once) ----
#pragma unroll
  for (int off = 1; off < 64; off <<= 1) mse += __shfl_xor(mse, off, 64);
  if (l == 0) {
    out[0] = (float)(mse / (double)((NSTEPS + 1) * NX));
  }
}

extern "C" void kernel_launch(void* const* d_in, const int* in_sizes, int n_in,
                              void* d_out, int out_size, void* d_ws, size_t ws_size,
                              hipStream_t stream) {
  const float* x0 = (const float*)d_in[0];
  const float* xref = (const float*)d_in[1];
  const float* useq = (const float*)d_in[2];
  const float* A = (const float*)d_in[3];
  const float* B = (const float*)d_in[4];
  float* out = (float*)d_out;

  nmpc_rollout_kernel<<<dim3(1), dim3(64), 0, stream>>>(x0, xref, useq, A, B, out);
}

// Round 10
// 1461.495 us; speedup vs baseline: 4.5004x; 4.5004x over previous
//
#include <hip/hip_runtime.h>

#define NX 128
#define NSTEPS 4096

typedef float f2 __attribute__((ext_vector_type(2)));
typedef float f4 __attribute__((ext_vector_type(4)));

union F4 {
  f4 v;
  f2 h[2];
  float s[4];
};

// packed fp32 FMA: d = a*b + d on both 32-bit halves (full-rate on CDNA)
__device__ __forceinline__ void pk_fma(f2& d, f2 a, f2 b) {
  asm("v_pk_fma_f32 %0, %1, %2, %0" : "+v"(d) : "v"(a), "v"(b));
}

// self + DPP(oth): role-split butterfly stage (all VALU pipe)
template <int CTRL>
__device__ __forceinline__ float dpp_add(float self, float oth) {
  int i = __float_as_int(oth);
  int s = __builtin_amdgcn_update_dpp(i, i, CTRL, 0xf, 0xf, false);
  return self + __int_as_float(s);
}

// 2 waves, R=8 rows x C=16 cols per lane: A-frag 128 VGPR (fits the 256 cap
// that killed round 9), LDS x-traffic 8 KB/step (half of R6), 2-wave barrier.
__launch_bounds__(128, 1)
__global__ void nmpc_rollout_kernel(const float* __restrict__ x0,
                                    const float* __restrict__ xref,
                                    const float* __restrict__ useq,
                                    const float* __restrict__ A,
                                    const float* __restrict__ B,
                                    float* __restrict__ out) {
  // x stored as 8 slices of 16 floats padded to 20 words: per ds_read_b128
  // the 8 broadcast groups start at banks {0,20,8,28,16,4,24,12} (disjoint).
  __shared__ __align__(16) float xs0[160];
  __shared__ __align__(16) float xs1[160];
  __shared__ float2 us[NSTEPS];  // interleaved (u0[s], u1[s]) pairs, 32KB
  __shared__ double wsum[2];

  const int t = threadIdx.x;
  const int l = t & 63;
  const int w = t >> 6;
  // part index from lane bits {0,1,3} -> reduce masks {1,2,8}, all DPP:
  // xor1 = quad_perm[1,0,3,2], xor2 = quad_perm[2,3,0,1], xor8 = row_ror:8.
  const int p = (l & 3) | ((l >> 1) & 4);
  const int gl = ((l >> 2) & 1) | ((l >> 3) & 6);  // lane bits {2,4,5}
  const int g = 8 * w + gl;                        // row-group 0..15
  const int r = 8 * g + p;                         // the row this lane owns

  // ---- one-time staging of useq into LDS (interleaved pairs) ----
#pragma unroll
  for (int k = 0; k < NSTEPS / 128; ++k) {
    int idx = k * 128 + t;
    us[idx] = make_float2(useq[idx], useq[NSTEPS + idx]);
  }

  // ---- A fragment: rows 8g..8g+7, cols 16p..16p+15, prescaled by 2*log2(e)
  // so the dot product feeds exp2 directly. 32 f4 = 128 VGPRs. ----
  const float K = 2.8853900817779268f;
  F4 a[8][4];
#pragma unroll
  for (int j = 0; j < 8; ++j) {
#pragma unroll
    for (int q = 0; q < 4; ++q) {
      a[j][q].v = *(const f4*)(A + (8 * g + j) * NX + 16 * p + 4 * q) * K;
    }
  }
  const float b0 = B[2 * r] * K;
  const float b1 = B[2 * r + 1] * K;

  // fp64 master state (accuracy anchor); xf = f32 image used by the matvec.
  double xc = (double)x0[r];
  float xf = (float)xc;
  double mse;
  {
    double d = xc - (double)xref[r];
    mse = d * d;  // each row counted exactly once
  }
  xs0[20 * (r >> 4) + (r & 15)] = xf;
  __syncthreads();  // once, outside the hot loop

  // ---- 4-deep rolling prefetch of xref rows (consumed off the x-chain) ----
  float xr0 = xref[1 * NX + r];
  float xr1 = xref[2 * NX + r];
  float xr2 = xref[3 * NX + r];
  float xr3 = xref[4 * NX + r];

  auto step = [&](const float* __restrict__ src, float* __restrict__ dst, int s) {
    // ---- own 16-col x slice: 4x ds_read_b128, conflict-free ----
    const f4* xb = (const f4*)(src + 20 * p);
    F4 xv0, xv1, xv2, xv3;
    xv0.v = xb[0]; xv1.v = xb[1]; xv2.v = xb[2]; xv3.v = xb[3];
    float2 uv = us[s];  // broadcast; consumed off-chain
    int nref = (s + 5 <= NSTEPS) ? (s + 5) : NSTEPS;
    float xnew = xref[nref * NX + r];

    // ---- 8 rows x 16 cols: 64 pk_fma in 16 independent chains ----
    f2 ce[8], co[8];
#pragma unroll
    for (int j = 0; j < 8; ++j) { ce[j] = (f2)(0.f); co[j] = (f2)(0.f); }
#pragma unroll
    for (int j = 0; j < 8; ++j) {
      pk_fma(ce[j], a[j][0].h[0], xv0.h[0]);
      pk_fma(co[j], a[j][0].h[1], xv0.h[1]);
      pk_fma(ce[j], a[j][1].h[0], xv1.h[0]);
      pk_fma(co[j], a[j][1].h[1], xv1.h[1]);
      pk_fma(ce[j], a[j][2].h[0], xv2.h[0]);
      pk_fma(co[j], a[j][2].h[1], xv2.h[1]);
      pk_fma(ce[j], a[j][3].h[0], xv3.h[0]);
      pk_fma(co[j], a[j][3].h[1], xv3.h[1]);
    }
    float bu = fmaf(b1, uv.y, b0 * uv.x);  // off critical path

    float acc[8];
#pragma unroll
    for (int j = 0; j < 8; ++j) {
      f2 h = ce[j] + co[j];
      acc[j] = h.x + h.y;
    }

    // ---- role-split butterfly over the 8 parts (lane-XOR masks 1,2,8):
    // each stage halves live accs; lane ends with the full sum of row 8g+p.
    const bool q0 = (p & 1), q1 = (p & 2), q2 = (p & 4);
    float s0 = dpp_add<0xB1>(q0 ? acc[1] : acc[0], q0 ? acc[0] : acc[1]);
    float s1 = dpp_add<0xB1>(q0 ? acc[3] : acc[2], q0 ? acc[2] : acc[3]);
    float s2 = dpp_add<0xB1>(q0 ? acc[5] : acc[4], q0 ? acc[4] : acc[5]);
    float s3 = dpp_add<0xB1>(q0 ? acc[7] : acc[6], q0 ? acc[6] : acc[7]);
    float u0 = dpp_add<0x4E>(q1 ? s1 : s0, q1 ? s0 : s1);
    float u1 = dpp_add<0x4E>(q1 ? s3 : s2, q1 ? s2 : s3);
    float sum = dpp_add<0x128>(q2 ? u1 : u0, q2 ? u0 : u1);  // row_ror:8 = xor8

    // ---- tail: every lane finalizes exactly its own row (no divergence) ----
    float zk = sum + bu;  // already scaled by 2*log2(e)
    float e = __builtin_amdgcn_exp2f(zk);
    float xd = fmaf(-2.f, __builtin_amdgcn_rcpf(e + 1.f), 1.f);  // tanh
    float nf = xf + xd;  // f32 anchor: shortest possible store chain
    dst[20 * (r >> 4) + (r & 15)] = nf;

    // raw barrier: drain LDS ops only; vmem prefetches stay in flight
    asm volatile("s_waitcnt lgkmcnt(0)" ::: "memory");
    __builtin_amdgcn_s_barrier();
    asm volatile("" ::: "memory");

    // shadow work after the barrier: fills the next step's ds_read latency
    xc += (double)xd;  // f64 master state
    xf = (float)xc;    // re-anchor
    double d = xc - (double)xr0;  // xr0 loaded 4 steps ago
    mse = fma(d, d, mse);

    xr0 = xr1; xr1 = xr2; xr2 = xr3; xr3 = xnew;  // SSA-renamed by unroll
  };

#pragma unroll 1
  for (int s = 0; s < NSTEPS; s += 2) {
    step(xs0, xs1, s);
    step(xs1, xs0, s + 1);
  }

  // ---- final reduction (each row counted exactly once) ----
#pragma unroll
  for (int off = 1; off < 64; off <<= 1) mse += __shfl_xor(mse, off, 64);
  if (l == 0) wsum[w] = mse;
  __syncthreads();
  if (t == 0) {
    out[0] = (float)((wsum[0] + wsum[1]) / (double)((NSTEPS + 1) * NX));
  }
}

extern "C" void kernel_launch(void* const* d_in, const int* in_sizes, int n_in,
                              void* d_out, int out_size, void* d_ws, size_t ws_size,
                              hipStream_t stream) {
  const float* x0 = (const float*)d_in[0];
  const float* xref = (const float*)d_in[1];
  const float* useq = (const float*)d_in[2];
  const float* A = (const float*)d_in[3];
  const float* B = (const float*)d_in[4];
  float* out = (float*)d_out;

  nmpc_rollout_kernel<<<dim3(1), dim3(128), 0, stream>>>(x0, xref, useq, A, B, out);
}

// Round 11
// 1289.833 us; speedup vs baseline: 5.0994x; 1.1331x over previous
//
#include <hip/hip_runtime.h>

#define NX 128
#define NSTEPS 4096

typedef float f2 __attribute__((ext_vector_type(2)));
typedef float f4 __attribute__((ext_vector_type(4)));

union F4 {
  f4 v;
  f2 h[2];
  float s[4];
};

// packed fp32 FMA: d = a*b + d on both 32-bit halves (full-rate on CDNA)
__device__ __forceinline__ void pk_fma(f2& d, f2 a, f2 b) {
  asm("v_pk_fma_f32 %0, %1, %2, %0" : "+v"(d) : "v"(a), "v"(b));
}

// role-split butterfly stage: self + DPP-moved(oth)
template <int CTRL>
__device__ __forceinline__ float dpp_add(float self, float oth) {
  int i = __float_as_int(oth);
  int s = __builtin_amdgcn_update_dpp(i, i, CTRL, 0xf, 0xf, false);
  return self + __int_as_float(s);
}
template <int CTRL>
__device__ __forceinline__ float dpp_mov(float v) {
  int i = __float_as_int(v);
  return __int_as_float(__builtin_amdgcn_update_dpp(i, i, CTRL, 0xf, 0xf, false));
}

// T=256 (FMA issue stays 64 cyc/SIMD), C=8 (DS return traffic 8 KB/step,
// half of R6). 16-part reduce: masks {1,2,8} role-split + xor4 via two DPP
// moves (xor7 then xor3). Tail numerics verbatim from the 1322us kernel.
__launch_bounds__(256, 1)
__global__ void nmpc_rollout_kernel(const float* __restrict__ x0,
                                    const float* __restrict__ xref,
                                    const float* __restrict__ useq,
                                    const float* __restrict__ A,
                                    const float* __restrict__ B,
                                    float* __restrict__ out) {
  // x stored as 16 slices of 8 floats at 12-word (48B) stride: b128 reads at
  // word 12*cp are 16B-aligned; banks 12cp%32 pair up at worst 2-way (free).
  __shared__ __align__(16) float xs0[192];
  __shared__ __align__(16) float xs1[192];
  __shared__ float2 us[NSTEPS];  // interleaved (u0[s], u1[s]) pairs, 32KB
  __shared__ double wsum[4];

  const int t = threadIdx.x;
  const int cp = t & 15;                      // column part 0..15 (8 cols)
  const int G = t >> 4;                       // row-group 0..15 (8 rows)
  const int j = (t & 3) | ((t >> 1) & 4);     // row-within-group from lane bits {0,1,3}
  const int r = 8 * G + j;                    // row this lane finalizes (2 copies: t, t^4)

  // ---- one-time staging of useq into LDS (interleaved pairs) ----
#pragma unroll
  for (int k = 0; k < NSTEPS / 256; ++k) {
    int idx = k * 256 + t;
    us[idx] = make_float2(useq[idx], useq[NSTEPS + idx]);
  }

  // ---- A fragment: rows 8G..8G+7, cols 8cp..8cp+7 -> 64 VGPRs ----
  F4 a[8][2];
#pragma unroll
  for (int jj = 0; jj < 8; ++jj) {
#pragma unroll
    for (int q = 0; q < 2; ++q) {
      a[jj][q].v = *(const f4*)(A + (8 * G + jj) * NX + 8 * cp + 4 * q);
    }
  }
  const float b0 = B[2 * r];
  const float b1 = B[2 * r + 1];

  // fp64 master state (accuracy anchor); LDS holds the f32 image.
  double x_cur = (double)x0[r];
  double mse;
  {
    double d = x_cur - (double)xref[r];
    mse = d * d;  // every row counted exactly twice (t and t^4) -> /2 at end
  }
  if ((t & 4) == 0) xs0[12 * (r >> 3) + (r & 7)] = (float)x_cur;
  __syncthreads();  // once, outside the hot loop

  // ---- 4-deep rolling prefetch of xref rows (consumed off the x-chain) ----
  float xr0 = xref[1 * NX + r];
  float xr1 = xref[2 * NX + r];
  float xr2 = xref[3 * NX + r];
  float xr3 = xref[4 * NX + r];

  auto step = [&](const float* __restrict__ src, float* __restrict__ dst, int s) {
    // ---- own 8-col x slice: 2x ds_read_b128, 16B-aligned, <=2-way ----
    const f4* xb = (const f4*)(src + 12 * cp);
    F4 xv0, xv1;
    xv0.v = xb[0];
    xv1.v = xb[1];
    float2 uv = us[s];  // broadcast; consumed off-chain
    int nref = (s + 5 <= NSTEPS) ? (s + 5) : NSTEPS;
    float xnew = xref[nref * NX + r];

    // ---- 8 rows x 8 cols: 32 pk_fma in 16 independent chains (depth 2) ----
    f2 ce[8], co[8];
#pragma unroll
    for (int jj = 0; jj < 8; ++jj) { ce[jj] = (f2)(0.f); co[jj] = (f2)(0.f); }
#pragma unroll
    for (int jj = 0; jj < 8; ++jj) {
      pk_fma(ce[jj], a[jj][0].h[0], xv0.h[0]);
      pk_fma(co[jj], a[jj][0].h[1], xv0.h[1]);
      pk_fma(ce[jj], a[jj][1].h[0], xv1.h[0]);
      pk_fma(co[jj], a[jj][1].h[1], xv1.h[1]);
    }
    float acc[8];
#pragma unroll
    for (int jj = 0; jj < 8; ++jj) {
      f2 h = ce[jj] + co[jj];
      acc[jj] = h.x + h.y;
    }

    // ---- 16-part role-split butterfly (lane-XOR masks 1,2,8, then 4) ----
    const bool q0 = (t & 1), q1 = (t & 2), q3 = (t & 8);
    float s0 = dpp_add<0xB1>(q0 ? acc[1] : acc[0], q0 ? acc[0] : acc[1]);
    float s1 = dpp_add<0xB1>(q0 ? acc[3] : acc[2], q0 ? acc[2] : acc[3]);
    float s2 = dpp_add<0xB1>(q0 ? acc[5] : acc[4], q0 ? acc[4] : acc[5]);
    float s3 = dpp_add<0xB1>(q0 ? acc[7] : acc[6], q0 ? acc[6] : acc[7]);
    float u0 = dpp_add<0x4E>(q1 ? s1 : s0, q1 ? s0 : s1);
    float u1 = dpp_add<0x4E>(q1 ? s3 : s2, q1 ? s2 : s3);
    float v = dpp_add<0x128>(q3 ? u1 : u0, q3 ? u0 : u1);  // row_ror:8 = xor8
    // final stage: xor4 composed from two DPP moves (xor7 then xor3); both
    // redundant lanes (t, t^4) end with the full dot of row r.
    float sum = v + dpp_mov<0x1B>(dpp_mov<0x141>(v));

    // ---- tail (verbatim numerics of the 1322us kernel) ----
    float zf = fmaf(b1, uv.y, fmaf(b0, uv.x, sum));
    float e = __builtin_amdgcn_exp2f(zf * 2.8853900817779268f);  // e^{2z}
    float xd = fmaf(-2.f, __builtin_amdgcn_rcpf(e + 1.f), 1.f);  // tanh
    x_cur += (double)xd;
    if ((t & 4) == 0) dst[12 * (r >> 3) + (r & 7)] = (float)x_cur;
    double d = x_cur - (double)xr0;  // xr0 loaded 4 steps ago
    mse = fma(d, d, mse);

    // raw barrier: drain LDS ops only; vmem prefetches stay in flight
    asm volatile("s_waitcnt lgkmcnt(0)" ::: "memory");
    __builtin_amdgcn_s_barrier();
    asm volatile("" ::: "memory");

    xr0 = xr1; xr1 = xr2; xr2 = xr3; xr3 = xnew;  // SSA-renamed by unroll
  };

#pragma unroll 1
  for (int s = 0; s < NSTEPS; s += 4) {
    step(xs0, xs1, s);
    step(xs1, xs0, s + 1);
    step(xs0, xs1, s + 2);
    step(xs1, xs0, s + 3);
  }

  // ---- final reduction (each row counted exactly twice -> /2) ----
#pragma unroll
  for (int off = 1; off < 64; off <<= 1) mse += __shfl_xor(mse, off, 64);
  if ((t & 63) == 0) wsum[t >> 6] = mse;
  __syncthreads();
  if (t == 0) {
    double tot = wsum[0] + wsum[1] + wsum[2] + wsum[3];
    out[0] = (float)(tot / (2.0 * (double)((NSTEPS + 1) * NX)));
  }
}

extern "C" void kernel_launch(void* const* d_in, const int* in_sizes, int n_in,
                              void* d_out, int out_size, void* d_ws, size_t ws_size,
                              hipStream_t stream) {
  const float* x0 = (const float*)d_in[0];
  const float* xref = (const float*)d_in[1];
  const float* useq = (const float*)d_in[2];
  const float* A = (const float*)d_in[3];
  const float* B = (const float*)d_in[4];
  float* out = (float*)d_out;

  nmpc_rollout_kernel<<<dim3(1), dim3(256), 0, stream>>>(x0, xref, useq, A, B, out);
}

// Round 12
// 1261.994 us; speedup vs baseline: 5.2119x; 1.0221x over previous
//
#include <hip/hip_runtime.h>

#define NX 128
#define NSTEPS 4096

typedef float f2 __attribute__((ext_vector_type(2)));
typedef float f4 __attribute__((ext_vector_type(4)));

union F4 {
  f4 v;
  f2 h[2];
  float s[4];
};

// packed fp32 FMA: d = a*b + d on both 32-bit halves (full-rate on CDNA)
__device__ __forceinline__ void pk_fma(f2& d, f2 a, f2 b) {
  asm("v_pk_fma_f32 %0, %1, %2, %0" : "+v"(d) : "v"(a), "v"(b));
}

// role-split butterfly stage: self + DPP-moved(oth)
template <int CTRL>
__device__ __forceinline__ float dpp_add(float self, float oth) {
  int i = __float_as_int(oth);
  int s = __builtin_amdgcn_update_dpp(i, i, CTRL, 0xf, 0xf, false);
  return self + __int_as_float(s);
}
template <int CTRL>
__device__ __forceinline__ float dpp_mov(float v) {
  int i = __float_as_int(v);
  return __int_as_float(__builtin_amdgcn_update_dpp(i, i, CTRL, 0xf, 0xf, false));
}

// T=256, C=8 (the 1290us R11 base) + chain-shortened tail:
//  - A,B prescaled by 2*log2(e): exp2 feeds directly off sum+bu (bu off-chain)
//  - pure-f32 state: store chain is (xf += xd) -> ds_write; no f64 add/cvt
//  - f64 MSE work moved after the barrier (shadow region)
__launch_bounds__(256, 1)
__global__ void nmpc_rollout_kernel(const float* __restrict__ x0,
                                    const float* __restrict__ xref,
                                    const float* __restrict__ useq,
                                    const float* __restrict__ A,
                                    const float* __restrict__ B,
                                    float* __restrict__ out) {
  // x stored as 16 slices of 8 floats at 12-word (48B) stride: b128 reads at
  // word 12*cp are 16B-aligned; banks 12cp%32 pair up at worst 2-way (free).
  __shared__ __align__(16) float xs0[192];
  __shared__ __align__(16) float xs1[192];
  __shared__ float2 us[NSTEPS];  // interleaved (u0[s], u1[s]) pairs, 32KB
  __shared__ double wsum[4];

  const int t = threadIdx.x;
  const int cp = t & 15;                   // column part 0..15 (8 cols)
  const int G = t >> 4;                    // row-group 0..15 (8 rows)
  const int j = (t & 3) | ((t >> 1) & 4);  // row-within-group, lane bits {0,1,3}
  const int r = 8 * G + j;                 // row finalized by lanes t and t^4

  // ---- one-time staging of useq into LDS (interleaved pairs) ----
#pragma unroll
  for (int k = 0; k < NSTEPS / 256; ++k) {
    int idx = k * 256 + t;
    us[idx] = make_float2(useq[idx], useq[NSTEPS + idx]);
  }

  // ---- A fragment: rows 8G..8G+7, cols 8cp..8cp+7, prescaled by 2*log2(e)
  // so the dot product feeds exp2 directly -> 64 VGPRs ----
  const float K = 2.8853900817779268f;
  F4 a[8][2];
#pragma unroll
  for (int jj = 0; jj < 8; ++jj) {
#pragma unroll
    for (int q = 0; q < 2; ++q) {
      a[jj][q].v = *(const f4*)(A + (8 * G + jj) * NX + 8 * cp + 4 * q) * K;
    }
  }
  const float b0 = B[2 * r] * K;
  const float b1 = B[2 * r + 1] * K;

  // pure-f32 state (saturation-dominated dynamics: tanh deriv ~0 on most
  // steps, so f32 state rounding does not amplify; margin is ~4 orders).
  float xf = x0[r];
  double mse;
  {
    double d = (double)(xf - xref[r]);
    mse = d * d;  // every row counted twice (t, t^4) -> /2 at the end
  }
  if ((t & 4) == 0) xs0[12 * (r >> 3) + (r & 7)] = xf;
  __syncthreads();  // once, outside the hot loop

  // ---- 4-deep rolling prefetch of xref rows (consumed off the x-chain) ----
  float xr0 = xref[1 * NX + r];
  float xr1 = xref[2 * NX + r];
  float xr2 = xref[3 * NX + r];
  float xr3 = xref[4 * NX + r];

  auto step = [&](const float* __restrict__ src, float* __restrict__ dst, int s) {
    // ---- own 8-col x slice: 2x ds_read_b128, 16B-aligned, <=2-way ----
    const f4* xb = (const f4*)(src + 12 * cp);
    F4 xv0, xv1;
    xv0.v = xb[0];
    xv1.v = xb[1];
    float2 uv = us[s];  // broadcast; consumed off-chain via bu
    int nref = (s + 5 <= NSTEPS) ? (s + 5) : NSTEPS;
    float xnew = xref[nref * NX + r];

    // ---- 8 rows x 8 cols: 32 pk_fma in 16 independent chains (depth 2) ----
    f2 ce[8], co[8];
#pragma unroll
    for (int jj = 0; jj < 8; ++jj) { ce[jj] = (f2)(0.f); co[jj] = (f2)(0.f); }
#pragma unroll
    for (int jj = 0; jj < 8; ++jj) {
      pk_fma(ce[jj], a[jj][0].h[0], xv0.h[0]);
      pk_fma(co[jj], a[jj][0].h[1], xv0.h[1]);
      pk_fma(ce[jj], a[jj][1].h[0], xv1.h[0]);
      pk_fma(co[jj], a[jj][1].h[1], xv1.h[1]);
    }
    float bu = fmaf(b1, uv.y, b0 * uv.x);  // off critical path (uv early)

    float acc[8];
#pragma unroll
    for (int jj = 0; jj < 8; ++jj) {
      f2 h = ce[jj] + co[jj];
      acc[jj] = h.x + h.y;
    }

    // ---- 16-part role-split butterfly (lane-XOR masks 1,2,8, then 4) ----
    const bool q0 = (t & 1), q1 = (t & 2), q3 = (t & 8);
    float s0 = dpp_add<0xB1>(q0 ? acc[1] : acc[0], q0 ? acc[0] : acc[1]);
    float s1 = dpp_add<0xB1>(q0 ? acc[3] : acc[2], q0 ? acc[2] : acc[3]);
    float s2 = dpp_add<0xB1>(q0 ? acc[5] : acc[4], q0 ? acc[4] : acc[5]);
    float s3 = dpp_add<0xB1>(q0 ? acc[7] : acc[6], q0 ? acc[6] : acc[7]);
    float u0 = dpp_add<0x4E>(q1 ? s1 : s0, q1 ? s0 : s1);
    float u1 = dpp_add<0x4E>(q1 ? s3 : s2, q1 ? s2 : s3);
    float v = dpp_add<0x128>(q3 ? u1 : u0, q3 ? u0 : u1);  // row_ror:8 = xor8
    // xor4 via two DPP moves (xor7 then xor3): both copies get the full sum
    float sum = v + dpp_mov<0x1B>(dpp_mov<0x141>(v));

    // ---- shortest tail: add, exp2, add, rcp, fma, add, store ----
    float zk = sum + bu;  // already scaled by 2*log2(e)
    float e = __builtin_amdgcn_exp2f(zk);
    float xd = fmaf(-2.f, __builtin_amdgcn_rcpf(e + 1.f), 1.f);  // tanh
    float xf_new = xf + xd;
    if ((t & 4) == 0) dst[12 * (r >> 3) + (r & 7)] = xf_new;

    // raw barrier: drain LDS ops only; vmem prefetches stay in flight
    asm volatile("s_waitcnt lgkmcnt(0)" ::: "memory");
    __builtin_amdgcn_s_barrier();
    asm volatile("" ::: "memory");

    // shadow work after the barrier (fills next step's ds_read latency)
    xf = xf_new;
    double d = (double)(xf_new - xr0);  // xr0 loaded 4 steps ago
    mse = fma(d, d, mse);

    xr0 = xr1; xr1 = xr2; xr2 = xr3; xr3 = xnew;  // SSA-renamed by unroll
  };

#pragma unroll 1
  for (int s = 0; s < NSTEPS; s += 4) {
    step(xs0, xs1, s);
    step(xs1, xs0, s + 1);
    step(xs0, xs1, s + 2);
    step(xs1, xs0, s + 3);
  }

  // ---- final reduction (each row counted exactly twice -> /2) ----
#pragma unroll
  for (int off = 1; off < 64; off <<= 1) mse += __shfl_xor(mse, off, 64);
  if ((t & 63) == 0) wsum[t >> 6] = mse;
  __syncthreads();
  if (t == 0) {
    double tot = wsum[0] + wsum[1] + wsum[2] + wsum[3];
    out[0] = (float)(tot / (2.0 * (double)((NSTEPS + 1) * NX)));
  }
}

extern "C" void kernel_launch(void* const* d_in, const int* in_sizes, int n_in,
                              void* d_out, int out_size, void* d_ws, size_t ws_size,
                              hipStream_t stream) {
  const float* x0 = (const float*)d_in[0];
  const float* xref = (const float*)d_in[1];
  const float* useq = (const float*)d_in[2];
  const float* A = (const float*)d_in[3];
  const float* B = (const float*)d_in[4];
  float* out = (float*)d_out;

  nmpc_rollout_kernel<<<dim3(1), dim3(256), 0, stream>>>(x0, xref, useq, A, B, out);
}

// Round 13
// 1153.958 us; speedup vs baseline: 5.6998x; 1.0936x over previous
//
#include <hip/hip_runtime.h>

#define NX 128
#define NSTEPS 4096

typedef float f2 __attribute__((ext_vector_type(2)));
typedef float f4 __attribute__((ext_vector_type(4)));

union F4 {
  f4 v;
  f2 h[2];
  float s[4];
};

// packed fp32 FMA: d = a*b + d on both 32-bit halves (full-rate on CDNA)
__device__ __forceinline__ void pk_fma(f2& d, f2 a, f2 b) {
  asm("v_pk_fma_f32 %0, %1, %2, %0" : "+v"(d) : "v"(a), "v"(b));
}

// self + DPP-moved(oth): one butterfly stage, 2 VALU inst, no selects
template <int CTRL>
__device__ __forceinline__ float dpp_add(float self, float oth) {
  int i = __float_as_int(oth);
  int s = __builtin_amdgcn_update_dpp(i, i, CTRL, 0xf, 0xf, false);
  return self + __int_as_float(s);
}
template <int CTRL>
__device__ __forceinline__ float dpp_mov(float v) {
  int i = __float_as_int(v);
  return __int_as_float(__builtin_amdgcn_update_dpp(i, i, CTRL, 0xf, 0xf, false));
}

// T=256, C=8 (R12 base, 1262us) + select-free swap-encoded butterfly:
// lane t loads a[jj] from row 8G + (jj ^ j)  (j = own row-within-group),
// so every reduce stage is a uniform acc_even + dpp(acc_odd) — the 14
// cndmasks of the role-split version vanish; the reduction tree (and hence
// the floating-point result) is bit-identical.
__launch_bounds__(256, 1)
__global__ void nmpc_rollout_kernel(const float* __restrict__ x0,
                                    const float* __restrict__ xref,
                                    const float* __restrict__ useq,
                                    const float* __restrict__ A,
                                    const float* __restrict__ B,
                                    float* __restrict__ out) {
  // x stored as 16 slices of 8 floats at 12-word (48B) stride: b128 reads at
  // word 12*cp are 16B-aligned; banks 12cp%32 pair up at worst 2-way (free).
  __shared__ __align__(16) float xs0[192];
  __shared__ __align__(16) float xs1[192];
  __shared__ float2 us[NSTEPS];  // interleaved (u0[s], u1[s]) pairs, 32KB
  __shared__ double wsum[4];

  const int t = threadIdx.x;
  const int cp = t & 15;                   // column part 0..15 (8 cols)
  const int G = t >> 4;                    // row-group 0..15 (8 rows)
  const int j = (t & 3) | ((t >> 1) & 4);  // own row-within-group (bits 0,1,3)
  const int r = 8 * G + j;                 // row finalized by lanes t and t^4

  // ---- one-time staging of useq into LDS (interleaved pairs) ----
#pragma unroll
  for (int k = 0; k < NSTEPS / 256; ++k) {
    int idx = k * 256 + t;
    us[idx] = make_float2(useq[idx], useq[NSTEPS + idx]);
  }

  // ---- A fragment, swap-encoded rows: a[jj] <- row 8G + (jj ^ j),
  // cols 8cp..8cp+7, prescaled by 2*log2(e) -> 64 VGPRs ----
  const float K = 2.8853900817779268f;
  F4 a[8][2];
#pragma unroll
  for (int jj = 0; jj < 8; ++jj) {
#pragma unroll
    for (int q = 0; q < 2; ++q) {
      a[jj][q].v = *(const f4*)(A + (8 * G + (jj ^ j)) * NX + 8 * cp + 4 * q) * K;
    }
  }
  const float b0 = B[2 * r] * K;
  const float b1 = B[2 * r + 1] * K;

  // pure-f32 state (saturation-dominated dynamics; margin ~4 orders)
  float xf = x0[r];
  double mse;
  {
    double d = (double)(xf - xref[r]);
    mse = d * d;  // every row counted twice (t, t^4) -> /2 at the end
  }
  if ((t & 4) == 0) xs0[12 * (r >> 3) + (r & 7)] = xf;
  __syncthreads();  // once, outside the hot loop

  // ---- 4-deep rolling prefetch of xref rows (consumed off the x-chain) ----
  float xr0 = xref[1 * NX + r];
  float xr1 = xref[2 * NX + r];
  float xr2 = xref[3 * NX + r];
  float xr3 = xref[4 * NX + r];

  auto step = [&](const float* __restrict__ src, float* __restrict__ dst, int s) {
    // ---- own 8-col x slice: 2x ds_read_b128, 16B-aligned, <=2-way ----
    const f4* xb = (const f4*)(src + 12 * cp);
    F4 xv0, xv1;
    xv0.v = xb[0];
    xv1.v = xb[1];
    float2 uv = us[s];  // broadcast; consumed off-chain via bu
    int nref = (s + 5 <= NSTEPS) ? (s + 5) : NSTEPS;
    float xnew = xref[nref * NX + r];

    // ---- 8 rows x 8 cols: 32 pk_fma in 16 independent chains (depth 2) ----
    f2 ce[8], co[8];
#pragma unroll
    for (int jj = 0; jj < 8; ++jj) { ce[jj] = (f2)(0.f); co[jj] = (f2)(0.f); }
#pragma unroll
    for (int jj = 0; jj < 8; ++jj) {
      pk_fma(ce[jj], a[jj][0].h[0], xv0.h[0]);
      pk_fma(co[jj], a[jj][0].h[1], xv0.h[1]);
      pk_fma(ce[jj], a[jj][1].h[0], xv1.h[0]);
      pk_fma(co[jj], a[jj][1].h[1], xv1.h[1]);
    }
    float bu = fmaf(b1, uv.y, b0 * uv.x);  // off critical path (uv early)

    float acc[8];
#pragma unroll
    for (int jj = 0; jj < 8; ++jj) {
      f2 h = ce[jj] + co[jj];
      acc[jj] = h.x + h.y;
    }

    // ---- select-free butterfly: 17 inst, all uniform (rows swap-encoded) ----
    float m0 = dpp_add<0xB1>(acc[0], acc[1]);   // xor1: parts p,p^1
    float m1 = dpp_add<0xB1>(acc[2], acc[3]);
    float m2 = dpp_add<0xB1>(acc[4], acc[5]);
    float m3 = dpp_add<0xB1>(acc[6], acc[7]);
    float w0 = dpp_add<0x4E>(m0, m1);           // xor2
    float w1 = dpp_add<0x4E>(m2, m3);
    float fv = dpp_add<0x128>(w0, w1);          // row_ror:8 = xor8
    float sum = fv + dpp_mov<0x1B>(dpp_mov<0x141>(fv));  // xor4 = xor7.xor3

    // ---- shortest tail: add, exp2, add, rcp, fma, add, store ----
    float zk = sum + bu;  // already scaled by 2*log2(e)
    float e = __builtin_amdgcn_exp2f(zk);
    float xd = fmaf(-2.f, __builtin_amdgcn_rcpf(e + 1.f), 1.f);  // tanh
    float xf_new = xf + xd;
    if ((t & 4) == 0) dst[12 * (r >> 3) + (r & 7)] = xf_new;

    // f64 MSE work here: overlaps the ds_write ack the waitcnt stalls on
    xf = xf_new;
    double d = (double)(xf_new - xr0);  // xr0 loaded 4 steps ago
    mse = fma(d, d, mse);
    xr0 = xr1; xr1 = xr2; xr2 = xr3; xr3 = xnew;

    // raw barrier: drain LDS ops only; vmem prefetches stay in flight
    asm volatile("s_waitcnt lgkmcnt(0)" ::: "memory");
    __builtin_amdgcn_s_barrier();
    asm volatile("" ::: "memory");
  };

#pragma unroll 1
  for (int s = 0; s < NSTEPS; s += 4) {
    step(xs0, xs1, s);
    step(xs1, xs0, s + 1);
    step(xs0, xs1, s + 2);
    step(xs1, xs0, s + 3);
  }

  // ---- final reduction (each row counted exactly twice -> /2) ----
#pragma unroll
  for (int off = 1; off < 64; off <<= 1) mse += __shfl_xor(mse, off, 64);
  if ((t & 63) == 0) wsum[t >> 6] = mse;
  __syncthreads();
  if (t == 0) {
    double tot = wsum[0] + wsum[1] + wsum[2] + wsum[3];
    out[0] = (float)(tot / (2.0 * (double)((NSTEPS + 1) * NX)));
  }
}

extern "C" void kernel_launch(void* const* d_in, const int* in_sizes, int n_in,
                              void* d_out, int out_size, void* d_ws, size_t ws_size,
                              hipStream_t stream) {
  const float* x0 = (const float*)d_in[0];
  const float* xref = (const float*)d_in[1];
  const float* useq = (const float*)d_in[2];
  const float* A = (const float*)d_in[3];
  const float* B = (const float*)d_in[4];
  float* out = (float*)d_out;

  nmpc_rollout_kernel<<<dim3(1), dim3(256), 0, stream>>>(x0, xref, useq, A, B, out);
}

// Round 15
// 1067.738 us; speedup vs baseline: 6.1601x; 1.0808x over previous
//
#include <hip/hip_runtime.h>

#define NX 128
#define NSTEPS 4096

typedef float f2 __attribute__((ext_vector_type(2)));
typedef float f4 __attribute__((ext_vector_type(4)));

union F4 {
  f4 v;
  f2 h[2];
  float s[4];
};

// packed fp32 FMA: d = a*b + d on both 32-bit halves (full-rate on CDNA)
__device__ __forceinline__ void pk_fma(f2& d, f2 a, f2 b) {
  asm("v_pk_fma_f32 %0, %1, %2, %0" : "+v"(d) : "v"(a), "v"(b));
}

// Hazard-safe DPP stages via compiler intrinsics (the compiler's hazard
// recognizer inserts the required VALU->DPP wait states; R14's fused
// v_add_f32_dpp inline asm bypassed it and corrupted the reduce).
template <int CTRL>
__device__ __forceinline__ float dpp_add(float self, float oth) {
  int i = __float_as_int(oth);
  int s = __builtin_amdgcn_update_dpp(i, i, CTRL, 0xf, 0xf, false);
  return self + __int_as_float(s);
}
template <int CTRL>
__device__ __forceinline__ float dpp_mov(float v) {
  int i = __float_as_int(v);
  return __int_as_float(__builtin_amdgcn_update_dpp(i, i, CTRL, 0xf, 0xf, false));
}

// T=256, C=8, swap-encoded select-free butterfly (R13 base) + R14's audited
// cuts: merged 8-chain FMA, bu injected at chain-0 init, xf1 tail, f32 MSE,
// unconditional dual store. Butterfly restored to builtin (hazard-safe) form.
__launch_bounds__(256, 1)
__global__ void nmpc_rollout_kernel(const float* __restrict__ x0,
                                    const float* __restrict__ xref,
                                    const float* __restrict__ useq,
                                    const float* __restrict__ A,
                                    const float* __restrict__ B,
                                    float* __restrict__ out) {
  // x stored as 16 slices of 8 floats at 12-word (48B) stride: b128 reads at
  // word 12*cp are 16B-aligned; banks pair at worst 2-way (free).
  __shared__ __align__(16) float xs0[192];
  __shared__ __align__(16) float xs1[192];
  __shared__ float2 us[NSTEPS];  // interleaved (u0[s], u1[s]) pairs, 32KB
  __shared__ double wsum[4];

  const int t = threadIdx.x;
  const int cp = t & 15;                   // column part 0..15 (8 cols)
  const int G = t >> 4;                    // row-group 0..15 (8 rows)
  const int j = (t & 3) | ((t >> 1) & 4);  // own row-within-group (bits 0,1,3)
  const int r = 8 * G + j;                 // row finalized by lanes t and t^4

  // ---- one-time staging of useq into LDS (interleaved pairs) ----
#pragma unroll
  for (int k = 0; k < NSTEPS / 256; ++k) {
    int idx = k * 256 + t;
    us[idx] = make_float2(useq[idx], useq[NSTEPS + idx]);
  }

  // ---- A fragment, swap-encoded rows: a[jj] <- row 8G + (jj ^ j),
  // cols 8cp..8cp+7, prescaled by 2*log2(e) -> 64 VGPRs ----
  const float K = 2.8853900817779268f;
  F4 a[8][2];
#pragma unroll
  for (int jj = 0; jj < 8; ++jj) {
#pragma unroll
    for (int q = 0; q < 2; ++q) {
      a[jj][q].v = *(const f4*)(A + (8 * G + (jj ^ j)) * NX + 8 * cp + 4 * q) * K;
    }
  }
  const float b0 = B[2 * r] * K;
  const float b1 = B[2 * r + 1] * K;

  // pure-f32 state; xf1 = xf + 1 maintained in shadow for the fma tail.
  float xf = x0[r];
  float xf1 = xf + 1.f;
  float msef;
  {
    float d = xf - xref[r];
    msef = d * d;  // every row counted twice (t, t^4) -> /2 at the end
  }
  xs0[12 * (r >> 3) + (r & 7)] = xf;  // dual write, identical values: benign
  __syncthreads();  // once, outside the hot loop

  // ---- 4-deep rolling prefetch of xref rows (consumed off the x-chain) ----
  float xr0 = xref[1 * NX + r];
  float xr1 = xref[2 * NX + r];
  float xr2 = xref[3 * NX + r];
  float xr3 = xref[4 * NX + r];

  auto step = [&](const float* __restrict__ src, float* __restrict__ dst, int s) {
    // ---- own 8-col x slice: 2x ds_read_b128, 16B-aligned, <=2-way ----
    const f4* xb = (const f4*)(src + 12 * cp);
    F4 xv0, xv1;
    xv0.v = xb[0];
    xv1.v = xb[1];
    float2 uv = us[s];
    int nref = (s + 5 <= NSTEPS) ? (s + 5) : NSTEPS;
    float xnew = xref[nref * NX + r];

    // bu enters through chain-0's accumulator init, exactly once per row
    // (only on the t&4==0 copy); it reaches both redundant lanes' sums via
    // the final xor4 stage.
    float bu = fmaf(b1, uv.y, b0 * uv.x);
    f2 c[8];
    c[0].x = ((t & 4) == 0) ? bu : 0.f;
    c[0].y = 0.f;
#pragma unroll
    for (int jj = 1; jj < 8; ++jj) c[jj] = (f2)(0.f);

    // ---- 32 pk_fma in 8 chains (depth 4); chain 0 last (bu dep) ----
#pragma unroll
    for (int jj = 1; jj < 8; ++jj) {
      pk_fma(c[jj], a[jj][0].h[0], xv0.h[0]);
      pk_fma(c[jj], a[jj][0].h[1], xv0.h[1]);
      pk_fma(c[jj], a[jj][1].h[0], xv1.h[0]);
      pk_fma(c[jj], a[jj][1].h[1], xv1.h[1]);
    }
    pk_fma(c[0], a[0][0].h[0], xv0.h[0]);
    pk_fma(c[0], a[0][0].h[1], xv0.h[1]);
    pk_fma(c[0], a[0][1].h[0], xv1.h[0]);
    pk_fma(c[0], a[0][1].h[1], xv1.h[1]);

    float acc0 = c[0].x + c[0].y;
    float acc1 = c[1].x + c[1].y;
    float acc2 = c[2].x + c[2].y;
    float acc3 = c[3].x + c[3].y;
    float acc4 = c[4].x + c[4].y;
    float acc5 = c[5].x + c[5].y;
    float acc6 = c[6].x + c[6].y;
    float acc7 = c[7].x + c[7].y;

    // ---- select-free butterfly (swap-encoded rows), hazard-safe form ----
    float m0 = dpp_add<0xB1>(acc0, acc1);   // quad_perm [1,0,3,2]: xor1
    float m1 = dpp_add<0xB1>(acc2, acc3);
    float m2 = dpp_add<0xB1>(acc4, acc5);
    float m3 = dpp_add<0xB1>(acc6, acc7);
    float w0 = dpp_add<0x4E>(m0, m1);       // quad_perm [2,3,0,1]: xor2
    float w1 = dpp_add<0x4E>(m2, m3);
    float fv = dpp_add<0x128>(w0, w1);      // row_ror:8 = xor8
    float sum = fv + dpp_mov<0x1B>(dpp_mov<0x141>(fv));  // xor4 = xor3 o xor7

    // ---- tail: exp2 -> add -> rcp -> fma(into xf1) -> store ----
    float e = __builtin_amdgcn_exp2f(sum);  // sum pre-scaled by 2*log2(e)
    float xf_new = fmaf(-2.f, __builtin_amdgcn_rcpf(e + 1.f), xf1);
    dst[12 * (r >> 3) + (r & 7)] = xf_new;  // dual write, bit-identical

    // shadow work (overlaps the ds_write ack before the drain)
    xf1 = xf_new + 1.f;
    float dd = xf_new - xr0;  // xr0 loaded 4 steps ago
    msef = fmaf(dd, dd, msef);
    xr0 = xr1; xr1 = xr2; xr2 = xr3; xr3 = xnew;

    // raw barrier: drain LDS ops only; vmem prefetches stay in flight
    asm volatile("s_waitcnt lgkmcnt(0)" ::: "memory");
    __builtin_amdgcn_s_barrier();
    asm volatile("" ::: "memory");
  };

#pragma unroll 1
  for (int s = 0; s < NSTEPS; s += 4) {
    step(xs0, xs1, s);
    step(xs1, xs0, s + 1);
    step(xs0, xs1, s + 2);
    step(xs1, xs0, s + 3);
  }

  // ---- final reduction in f64 (each row counted exactly twice -> /2) ----
  double mse = (double)msef;
#pragma unroll
  for (int off = 1; off < 64; off <<= 1) mse += __shfl_xor(mse, off, 64);
  if ((t & 63) == 0) wsum[t >> 6] = mse;
  __syncthreads();
  if (t == 0) {
    double tot = wsum[0] + wsum[1] + wsum[2] + wsum[3];
    out[0] = (float)(tot / (2.0 * (double)((NSTEPS + 1) * NX)));
  }
}

extern "C" void kernel_launch(void* const* d_in, const int* in_sizes, int n_in,
                              void* d_out, int out_size, void* d_ws, size_t ws_size,
                              hipStream_t stream) {
  const float* x0 = (const float*)d_in[0];
  const float* xref = (const float*)d_in[1];
  const float* useq = (const float*)d_in[2];
  const float* A = (const float*)d_in[3];
  const float* B = (const float*)d_in[4];
  float* out = (float*)d_out;

  nmpc_rollout_kernel<<<dim3(1), dim3(256), 0, stream>>>(x0, xref, useq, A, B, out);
}

// Round 16
// 1051.321 us; speedup vs baseline: 6.2563x; 1.0156x over previous
//
#include <hip/hip_runtime.h>

#define NX 128
#define NSTEPS 4096

typedef float f2 __attribute__((ext_vector_type(2)));
typedef float f4 __attribute__((ext_vector_type(4)));

union F4 {
  f4 v;
  f2 h[2];
  float s[4];
};

// packed fp32 FMA: d = a*b + d on both 32-bit halves (full-rate on CDNA)
__device__ __forceinline__ void pk_fma(f2& d, f2 a, f2 b) {
  asm("v_pk_fma_f32 %0, %1, %2, %0" : "+v"(d) : "v"(a), "v"(b));
}

// Hazard-safe DPP stages via compiler intrinsics (R14 lesson: inline-asm
// v_add_f32_dpp bypasses the VALU->DPP hazard recognizer and corrupts lanes).
template <int CTRL>
__device__ __forceinline__ float dpp_add(float self, float oth) {
  int i = __float_as_int(oth);
  int s = __builtin_amdgcn_update_dpp(i, i, CTRL, 0xf, 0xf, false);
  return self + __int_as_float(s);
}
template <int CTRL>
__device__ __forceinline__ float dpp_mov(float v) {
  int i = __float_as_int(v);
  return __int_as_float(__builtin_amdgcn_update_dpp(i, i, CTRL, 0xf, 0xf, false));
}

// R15 base (1068us) with a one-step-rotated software pipeline: uv/xnew are
// issued a full step before use; the filler (mse, shifts, xf1, bu) sits in
// the post-barrier ds_read latency hole instead of the pre-barrier drain.
__launch_bounds__(256, 1)
__global__ void nmpc_rollout_kernel(const float* __restrict__ x0,
                                    const float* __restrict__ xref,
                                    const float* __restrict__ useq,
                                    const float* __restrict__ A,
                                    const float* __restrict__ B,
                                    float* __restrict__ out) {
  // x stored as 16 slices of 8 floats at 12-word (48B) stride: b128 reads at
  // word 12*cp are 16B-aligned; banks pair at worst 2-way (free).
  __shared__ __align__(16) float xs0[192];
  __shared__ __align__(16) float xs1[192];
  __shared__ float2 us[NSTEPS + 4];  // +4 pad: head reads us[s+1] unclamped
  __shared__ double wsum[4];

  const int t = threadIdx.x;
  const int cp = t & 15;                   // column part 0..15 (8 cols)
  const int G = t >> 4;                    // row-group 0..15 (8 rows)
  const int j = (t & 3) | ((t >> 1) & 4);  // own row-within-group (bits 0,1,3)
  const int r = 8 * G + j;                 // row finalized by lanes t and t^4

  // ---- one-time staging of useq into LDS (interleaved pairs) ----
#pragma unroll
  for (int k = 0; k < NSTEPS / 256; ++k) {
    int idx = k * 256 + t;
    us[idx] = make_float2(useq[idx], useq[NSTEPS + idx]);
  }
  if (t < 4) us[NSTEPS + t] = make_float2(0.f, 0.f);

  // ---- A fragment, swap-encoded rows: a[jj] <- row 8G + (jj ^ j),
  // cols 8cp..8cp+7, prescaled by 2*log2(e) -> 64 VGPRs ----
  const float K = 2.8853900817779268f;
  F4 a[8][2];
#pragma unroll
  for (int jj = 0; jj < 8; ++jj) {
#pragma unroll
    for (int q = 0; q < 2; ++q) {
      a[jj][q].v = *(const f4*)(A + (8 * G + (jj ^ j)) * NX + 8 * cp + 4 * q) * K;
    }
  }
  const float b0 = B[2 * r] * K;
  const float b1 = B[2 * r + 1] * K;

  // pure-f32 state; xlast = x_s carried for the deferred MSE term.
  float xf = x0[r];
  float xlast = xf;
  float xf1 = xf + 1.f;
  float msef = 0.f;  // step-0 term added by step 0's filler
  xs0[12 * (r >> 3) + (r & 7)] = xf;  // dual write, identical values: benign
  __syncthreads();  // once, outside the hot loop

  // ---- rotated-pipeline prologue: xr0..xr3 = xref rows 0..3, carry = row 4,
  // uv = u(0); all consumed at least one full step after issue ----
  float xr0 = xref[0 * NX + r];
  float xr1 = xref[1 * NX + r];
  float xr2 = xref[2 * NX + r];
  float xr3 = xref[3 * NX + r];
  float xcar = xref[4 * NX + r];
  float2 uv = us[0];

  auto step = [&](const float* __restrict__ src, float* __restrict__ dst, int s) {
    // ---- head: issue all memory ops for this step + next ----
    const f4* xb = (const f4*)(src + 12 * cp);
    F4 xv0, xv1;
    xv0.v = xb[0];                         // ds_read_b128 x2 (critical)
    xv1.v = xb[1];
    float2 uv_next = us[s + 1];            // ds read, consumed next filler
    int nref = (s + 5 <= NSTEPS) ? (s + 5) : NSTEPS;
    float xnew = xref[nref * NX + r];      // global, consumed next filler

    // ---- filler (covers ds_read latency; nothing here touches xv/uv_next/
    // xnew): previous step's MSE term, shifts, xf1, this step's bu ----
    float bu = fmaf(b1, uv.y, b0 * uv.x);  // uv is one step old
    float dd = xlast - xr0;                // xlast = x_s, xr0 = xref row s
    msef = fmaf(dd, dd, msef);
    xr0 = xr1; xr1 = xr2; xr2 = xr3; xr3 = xcar;  // xcar loaded last step
    xf1 = xlast + 1.f;
    f2 c[8];
    c[0].x = ((t & 4) == 0) ? bu : 0.f;
    c[0].y = 0.f;
#pragma unroll
    for (int jj = 1; jj < 8; ++jj) c[jj] = (f2)(0.f);

    // ---- 32 pk_fma in 8 chains (depth 4); chain 0 last (bu dep) ----
#pragma unroll
    for (int jj = 1; jj < 8; ++jj) {
      pk_fma(c[jj], a[jj][0].h[0], xv0.h[0]);
      pk_fma(c[jj], a[jj][0].h[1], xv0.h[1]);
      pk_fma(c[jj], a[jj][1].h[0], xv1.h[0]);
      pk_fma(c[jj], a[jj][1].h[1], xv1.h[1]);
    }
    pk_fma(c[0], a[0][0].h[0], xv0.h[0]);
    pk_fma(c[0], a[0][0].h[1], xv0.h[1]);
    pk_fma(c[0], a[0][1].h[0], xv1.h[0]);
    pk_fma(c[0], a[0][1].h[1], xv1.h[1]);

    float acc0 = c[0].x + c[0].y;
    float acc1 = c[1].x + c[1].y;
    float acc2 = c[2].x + c[2].y;
    float acc3 = c[3].x + c[3].y;
    float acc4 = c[4].x + c[4].y;
    float acc5 = c[5].x + c[5].y;
    float acc6 = c[6].x + c[6].y;
    float acc7 = c[7].x + c[7].y;

    // ---- select-free butterfly (swap-encoded rows), hazard-safe form ----
    float m0 = dpp_add<0xB1>(acc0, acc1);   // xor1
    float m1 = dpp_add<0xB1>(acc2, acc3);
    float m2 = dpp_add<0xB1>(acc4, acc5);
    float m3 = dpp_add<0xB1>(acc6, acc7);
    float w0 = dpp_add<0x4E>(m0, m1);       // xor2
    float w1 = dpp_add<0x4E>(m2, m3);
    float fv = dpp_add<0x128>(w0, w1);      // row_ror:8 = xor8
    float sum = fv + dpp_mov<0x1B>(dpp_mov<0x141>(fv));  // xor4 = xor3 o xor7

    // ---- tail: exp2 -> add -> rcp -> fma(into xf1) -> store ----
    float e = __builtin_amdgcn_exp2f(sum);  // sum pre-scaled by 2*log2(e)
    float xf_new = fmaf(-2.f, __builtin_amdgcn_rcpf(e + 1.f), xf1);
    dst[12 * (r >> 3) + (r & 7)] = xf_new;  // dual write, bit-identical
    xlast = xf_new;

    // raw barrier: drain LDS ops only; vmem prefetches stay in flight
    asm volatile("s_waitcnt lgkmcnt(0)" ::: "memory");
    __builtin_amdgcn_s_barrier();
    asm volatile("" ::: "memory");

    uv = uv_next;   // register renames (free under the 4x unroll)
    xcar = xnew;
  };

#pragma unroll 1
  for (int s = 0; s < NSTEPS; s += 4) {
    step(xs0, xs1, s);
    step(xs1, xs0, s + 1);
    step(xs0, xs1, s + 2);
    step(xs1, xs0, s + 3);
  }
  // pending final term: xlast = x_N, xr0 = xref row N
  {
    float dd = xlast - xr0;
    msef = fmaf(dd, dd, msef);
  }

  // ---- final reduction in f64 (each row counted exactly twice -> /2) ----
  double mse = (double)msef;
#pragma unroll
  for (int off = 1; off < 64; off <<= 1) mse += __shfl_xor(mse, off, 64);
  if ((t & 63) == 0) wsum[t >> 6] = mse;
  __syncthreads();
  if (t == 0) {
    double tot = wsum[0] + wsum[1] + wsum[2] + wsum[3];
    out[0] = (float)(tot / (2.0 * (double)((NSTEPS + 1) * NX)));
  }
}

extern "C" void kernel_launch(void* const* d_in, const int* in_sizes, int n_in,
                              void* d_out, int out_size, void* d_ws, size_t ws_size,
                              hipStream_t stream) {
  const float* x0 = (const float*)d_in[0];
  const float* xref = (const float*)d_in[1];
  const float* useq = (const float*)d_in[2];
  const float* A = (const float*)d_in[3];
  const float* B = (const float*)d_in[4];
  float* out = (float*)d_out;

  nmpc_rollout_kernel<<<dim3(1), dim3(256), 0, stream>>>(x0, xref, useq, A, B, out);
}

// Round 17
// 972.881 us; speedup vs baseline: 6.7607x; 1.0806x over previous
//
#include <hip/hip_runtime.h>

#define NX 128
#define NSTEPS 4096

typedef float f2 __attribute__((ext_vector_type(2)));
typedef float f4 __attribute__((ext_vector_type(4)));

union F4 {
  f4 v;
  f2 h[2];
  float s[4];
};

// packed fp32 FMA / MUL (full-rate on CDNA)
__device__ __forceinline__ void pk_fma(f2& d, f2 a, f2 b) {
  asm("v_pk_fma_f32 %0, %1, %2, %0" : "+v"(d) : "v"(a), "v"(b));
}
__device__ __forceinline__ f2 pk_mul(f2 a, f2 b) {
  f2 d;
  asm("v_pk_mul_f32 %0, %1, %2" : "=v"(d) : "v"(a), "v"(b));
  return d;
}

// DPP stages with bound_ctrl=1 and dead old value: all source lanes are
// valid for our patterns (quad_perms / row_ror:8 / half_mirror), so the
// semantics are unchanged — but this form lets LLVM's GCNDPPCombine fold
// mov_dpp+add into a single hazard-managed v_add_f32_dpp (the safe version
// of what R14's raw inline asm got wrong).
template <int CTRL>
__device__ __forceinline__ float dpp_add(float self, float oth) {
  int s = __builtin_amdgcn_update_dpp(0, __float_as_int(oth), CTRL, 0xf, 0xf, true);
  return self + __int_as_float(s);
}
template <int CTRL>
__device__ __forceinline__ float dpp_mov(float v) {
  return __int_as_float(
      __builtin_amdgcn_update_dpp(0, __float_as_int(v), CTRL, 0xf, 0xf, true));
}

// R16 base (1051us) + issue-count surgery: pk_mul accumulator init (kills 14
// zero-movs) and combine-friendly DPP butterfly.
__launch_bounds__(256, 1)
__global__ void nmpc_rollout_kernel(const float* __restrict__ x0,
                                    const float* __restrict__ xref,
                                    const float* __restrict__ useq,
                                    const float* __restrict__ A,
                                    const float* __restrict__ B,
                                    float* __restrict__ out) {
  // x stored as 16 slices of 8 floats at 12-word (48B) stride: b128 reads at
  // word 12*cp are 16B-aligned; banks pair at worst 2-way (free).
  __shared__ __align__(16) float xs0[192];
  __shared__ __align__(16) float xs1[192];
  __shared__ float2 us[NSTEPS + 4];  // +4 pad: head reads us[s+1] unclamped
  __shared__ double wsum[4];

  const int t = threadIdx.x;
  const int cp = t & 15;                   // column part 0..15 (8 cols)
  const int G = t >> 4;                    // row-group 0..15 (8 rows)
  const int j = (t & 3) | ((t >> 1) & 4);  // own row-within-group (bits 0,1,3)
  const int r = 8 * G + j;                 // row finalized by lanes t and t^4

  // ---- one-time staging of useq into LDS (interleaved pairs) ----
#pragma unroll
  for (int k = 0; k < NSTEPS / 256; ++k) {
    int idx = k * 256 + t;
    us[idx] = make_float2(useq[idx], useq[NSTEPS + idx]);
  }
  if (t < 4) us[NSTEPS + t] = make_float2(0.f, 0.f);

  // ---- A fragment, swap-encoded rows: a[jj] <- row 8G + (jj ^ j),
  // cols 8cp..8cp+7, prescaled by 2*log2(e) -> 64 VGPRs ----
  const float K = 2.8853900817779268f;
  F4 a[8][2];
#pragma unroll
  for (int jj = 0; jj < 8; ++jj) {
#pragma unroll
    for (int q = 0; q < 2; ++q) {
      a[jj][q].v = *(const f4*)(A + (8 * G + (jj ^ j)) * NX + 8 * cp + 4 * q) * K;
    }
  }
  const float b0 = B[2 * r] * K;
  const float b1 = B[2 * r + 1] * K;

  // pure-f32 state; xlast = x_s carried for the deferred MSE term.
  float xf = x0[r];
  float xlast = xf;
  float xf1 = xf + 1.f;
  float msef = 0.f;  // step-0 term added by step 0's filler
  xs0[12 * (r >> 3) + (r & 7)] = xf;  // dual write, identical values: benign
  __syncthreads();  // once, outside the hot loop

  // ---- rotated-pipeline prologue ----
  float xr0 = xref[0 * NX + r];
  float xr1 = xref[1 * NX + r];
  float xr2 = xref[2 * NX + r];
  float xr3 = xref[3 * NX + r];
  float xcar = xref[4 * NX + r];
  float2 uv = us[0];

  auto step = [&](const float* __restrict__ src, float* __restrict__ dst, int s) {
    // ---- head: issue all memory ops for this step + next ----
    const f4* xb = (const f4*)(src + 12 * cp);
    F4 xv0, xv1;
    xv0.v = xb[0];                         // ds_read_b128 x2 (critical)
    xv1.v = xb[1];
    float2 uv_next = us[s + 1];            // ds read, consumed next filler
    int nref = (s + 5 <= NSTEPS) ? (s + 5) : NSTEPS;
    float xnew = xref[nref * NX + r];      // global, consumed next filler

    // ---- filler (covers ds_read latency): previous step's MSE term,
    // shifts, xf1, this step's bu ----
    float bu = fmaf(b1, uv.y, b0 * uv.x);  // uv is one step old
    float dd = xlast - xr0;                // xlast = x_s, xr0 = xref row s
    msef = fmaf(dd, dd, msef);
    xr0 = xr1; xr1 = xr2; xr2 = xr3; xr3 = xcar;  // xcar loaded last step
    xf1 = xlast + 1.f;

    // chain-0 carries bu (t&4==0 copy only); reaches both copies via xor4.
    f2 c0;
    c0.x = ((t & 4) == 0) ? bu : 0.f;
    c0.y = 0.f;

    // ---- 32 pk-ops in 8 chains: chains 1..7 start with pk_mul (no
    // zero-init movs; fma(a,b,0) == a*b), chain 0 carries bu ----
    pk_fma(c0, a[0][0].h[0], xv0.h[0]);
    f2 c1 = pk_mul(a[1][0].h[0], xv0.h[0]);
    f2 c2 = pk_mul(a[2][0].h[0], xv0.h[0]);
    f2 c3 = pk_mul(a[3][0].h[0], xv0.h[0]);
    f2 c4 = pk_mul(a[4][0].h[0], xv0.h[0]);
    f2 c5 = pk_mul(a[5][0].h[0], xv0.h[0]);
    f2 c6 = pk_mul(a[6][0].h[0], xv0.h[0]);
    f2 c7 = pk_mul(a[7][0].h[0], xv0.h[0]);

    pk_fma(c0, a[0][0].h[1], xv0.h[1]);
    pk_fma(c1, a[1][0].h[1], xv0.h[1]);
    pk_fma(c2, a[2][0].h[1], xv0.h[1]);
    pk_fma(c3, a[3][0].h[1], xv0.h[1]);
    pk_fma(c4, a[4][0].h[1], xv0.h[1]);
    pk_fma(c5, a[5][0].h[1], xv0.h[1]);
    pk_fma(c6, a[6][0].h[1], xv0.h[1]);
    pk_fma(c7, a[7][0].h[1], xv0.h[1]);

    pk_fma(c0, a[0][1].h[0], xv1.h[0]);
    pk_fma(c1, a[1][1].h[0], xv1.h[0]);
    pk_fma(c2, a[2][1].h[0], xv1.h[0]);
    pk_fma(c3, a[3][1].h[0], xv1.h[0]);
    pk_fma(c4, a[4][1].h[0], xv1.h[0]);
    pk_fma(c5, a[5][1].h[0], xv1.h[0]);
    pk_fma(c6, a[6][1].h[0], xv1.h[0]);
    pk_fma(c7, a[7][1].h[0], xv1.h[0]);

    pk_fma(c0, a[0][1].h[1], xv1.h[1]);
    pk_fma(c1, a[1][1].h[1], xv1.h[1]);
    pk_fma(c2, a[2][1].h[1], xv1.h[1]);
    pk_fma(c3, a[3][1].h[1], xv1.h[1]);
    pk_fma(c4, a[4][1].h[1], xv1.h[1]);
    pk_fma(c5, a[5][1].h[1], xv1.h[1]);
    pk_fma(c6, a[6][1].h[1], xv1.h[1]);
    pk_fma(c7, a[7][1].h[1], xv1.h[1]);

    float acc0 = c0.x + c0.y;
    float acc1 = c1.x + c1.y;
    float acc2 = c2.x + c2.y;
    float acc3 = c3.x + c3.y;
    float acc4 = c4.x + c4.y;
    float acc5 = c5.x + c5.y;
    float acc6 = c6.x + c6.y;
    float acc7 = c7.x + c7.y;

    // ---- select-free butterfly (swap-encoded rows), combine-friendly ----
    float m0 = dpp_add<0xB1>(acc0, acc1);   // xor1
    float m1 = dpp_add<0xB1>(acc2, acc3);
    float m2 = dpp_add<0xB1>(acc4, acc5);
    float m3 = dpp_add<0xB1>(acc6, acc7);
    float w0 = dpp_add<0x4E>(m0, m1);       // xor2
    float w1 = dpp_add<0x4E>(m2, m3);
    float fv = dpp_add<0x128>(w0, w1);      // row_ror:8 = xor8
    float sum = dpp_add<0x1B>(fv, dpp_mov<0x141>(fv));  // xor4 = xor3 o xor7

    // ---- tail: exp2 -> add -> rcp -> fma(into xf1) -> store ----
    float e = __builtin_amdgcn_exp2f(sum);  // sum pre-scaled by 2*log2(e)
    float xf_new = fmaf(-2.f, __builtin_amdgcn_rcpf(e + 1.f), xf1);
    dst[12 * (r >> 3) + (r & 7)] = xf_new;  // dual write, bit-identical
    xlast = xf_new;

    // raw barrier: drain LDS ops only; vmem prefetches stay in flight
    asm volatile("s_waitcnt lgkmcnt(0)" ::: "memory");
    __builtin_amdgcn_s_barrier();
    asm volatile("" ::: "memory");

    uv = uv_next;   // register renames (free under the 4x unroll)
    xcar = xnew;
  };

#pragma unroll 1
  for (int s = 0; s < NSTEPS; s += 4) {
    step(xs0, xs1, s);
    step(xs1, xs0, s + 1);
    step(xs0, xs1, s + 2);
    step(xs1, xs0, s + 3);
  }
  // pending final term: xlast = x_N, xr0 = xref row N
  {
    float dd = xlast - xr0;
    msef = fmaf(dd, dd, msef);
  }

  // ---- final reduction in f64 (each row counted exactly twice -> /2) ----
  double mse = (double)msef;
#pragma unroll
  for (int off = 1; off < 64; off <<= 1) mse += __shfl_xor(mse, off, 64);
  if ((t & 63) == 0) wsum[t >> 6] = mse;
  __syncthreads();
  if (t == 0) {
    double tot = wsum[0] + wsum[1] + wsum[2] + wsum[3];
    out[0] = (float)(tot / (2.0 * (double)((NSTEPS + 1) * NX)));
  }
}

extern "C" void kernel_launch(void* const* d_in, const int* in_sizes, int n_in,
                              void* d_out, int out_size, void* d_ws, size_t ws_size,
                              hipStream_t stream) {
  const float* x0 = (const float*)d_in[0];
  const float* xref = (const float*)d_in[1];
  const float* useq = (const float*)d_in[2];
  const float* A = (const float*)d_in[3];
  const float* B = (const float*)d_in[4];
  float* out = (float*)d_out;

  nmpc_rollout_kernel<<<dim3(1), dim3(256), 0, stream>>>(x0, xref, useq, A, B, out);
}

// Round 18
// 946.729 us; speedup vs baseline: 6.9474x; 1.0276x over previous
//
#include <hip/hip_runtime.h>

#define NX 128
#define NSTEPS 4096

typedef float f2 __attribute__((ext_vector_type(2)));
typedef float f4 __attribute__((ext_vector_type(4)));

union F4 {
  f4 v;
  f2 h[2];
  float s[4];
};

// packed fp32 FMA / MUL (full-rate on CDNA)
__device__ __forceinline__ void pk_fma(f2& d, f2 a, f2 b) {
  asm("v_pk_fma_f32 %0, %1, %2, %0" : "+v"(d) : "v"(a), "v"(b));
}
__device__ __forceinline__ f2 pk_mul(f2 a, f2 b) {
  f2 d;
  asm("v_pk_mul_f32 %0, %1, %2" : "=v"(d) : "v"(a), "v"(b));
  return d;
}

// DPP add with bound_ctrl=1, dead old: combine-friendly (GCNDPPCombine can
// fold to a hazard-managed v_add_f32_dpp; R14 lesson — never hand-emit it).
template <int CTRL>
__device__ __forceinline__ float dpp_add(float self, float oth) {
  int s = __builtin_amdgcn_update_dpp(0, __float_as_int(oth), CTRL, 0xf, 0xf, true);
  return self + __int_as_float(s);
}

// R17 base (973us) + depth-4 butterfly over masks {1,2,7,8} (all single-DPP
// patterns; they generate the full 4-bit XOR group). j = t&7 is now the
// row-within-group; t&8 is the redundancy bit (lanes t, t^8 share a row).
__launch_bounds__(256, 1)
__global__ void nmpc_rollout_kernel(const float* __restrict__ x0,
                                    const float* __restrict__ xref,
                                    const float* __restrict__ useq,
                                    const float* __restrict__ A,
                                    const float* __restrict__ B,
                                    float* __restrict__ out) {
  // x stored as 16 slices of 8 floats at 12-word (48B) stride: b128 reads at
  // word 12*cp are 16B-aligned; banks pair at worst 2-way (free).
  __shared__ __align__(16) float xs0[192];
  __shared__ __align__(16) float xs1[192];
  __shared__ float2 us[NSTEPS + 4];  // +4 pad: head reads us[s+1] unclamped
  __shared__ double wsum[4];

  const int t = threadIdx.x;
  const int cp = t & 15;     // column part 0..15 (8 cols)
  const int G = t >> 4;      // row-group 0..15 (8 rows)
  const int j = t & 7;       // own row-within-group (bits 0,1,2)
  const int r = 8 * G + j;   // row finalized by lanes t and t^8

  // ---- one-time staging of useq into LDS (interleaved pairs) ----
#pragma unroll
  for (int k = 0; k < NSTEPS / 256; ++k) {
    int idx = k * 256 + t;
    us[idx] = make_float2(useq[idx], useq[NSTEPS + idx]);
  }
  if (t < 4) us[NSTEPS + t] = make_float2(0.f, 0.f);

  // ---- A fragment, swap-encoded rows: a[jj] <- row 8G + (jj ^ j),
  // cols 8cp..8cp+7, prescaled by 2*log2(e) -> 64 VGPRs ----
  const float K = 2.8853900817779268f;
  F4 a[8][2];
#pragma unroll
  for (int jj = 0; jj < 8; ++jj) {
#pragma unroll
    for (int q = 0; q < 2; ++q) {
      a[jj][q].v = *(const f4*)(A + (8 * G + (jj ^ j)) * NX + 8 * cp + 4 * q) * K;
    }
  }
  const float b0 = B[2 * r] * K;
  const float b1 = B[2 * r + 1] * K;

  // pure-f32 state; xlast = x_s carried for the deferred MSE term.
  float xf = x0[r];
  float xlast = xf;
  float xf1 = xf + 1.f;
  float msef = 0.f;  // step-0 term added by step 0's filler
  xs0[12 * (r >> 3) + (r & 7)] = xf;  // dual write, identical values: benign
  __syncthreads();  // once, outside the hot loop

  // ---- rotated-pipeline prologue ----
  float xr0 = xref[0 * NX + r];
  float xr1 = xref[1 * NX + r];
  float xr2 = xref[2 * NX + r];
  float xr3 = xref[3 * NX + r];
  float xcar = xref[4 * NX + r];
  float2 uv = us[0];

  auto step = [&](const float* __restrict__ src, float* __restrict__ dst, int s) {
    // ---- head: issue all memory ops for this step + next ----
    const f4* xb = (const f4*)(src + 12 * cp);
    F4 xv0, xv1;
    xv0.v = xb[0];                         // ds_read_b128 x2 (critical)
    xv1.v = xb[1];
    float2 uv_next = us[s + 1];            // ds read, consumed next filler
    int nref = (s + 5 <= NSTEPS) ? (s + 5) : NSTEPS;
    float xnew = xref[nref * NX + r];      // global, consumed next filler

    // ---- filler (covers ds_read latency): previous step's MSE term,
    // shifts, xf1, this step's bu ----
    float bu = fmaf(b1, uv.y, b0 * uv.x);  // uv is one step old
    float dd = xlast - xr0;                // xlast = x_s, xr0 = xref row s
    msef = fmaf(dd, dd, msef);
    xr0 = xr1; xr1 = xr2; xr2 = xr3; xr3 = xcar;  // xcar loaded last step
    xf1 = xlast + 1.f;

    // chain-0 carries bu (t&8==0 copy only); reaches both copies via xor8.
    f2 c0;
    c0.x = ((t & 8) == 0) ? bu : 0.f;
    c0.y = 0.f;

    // ---- 32 pk-ops in 8 chains: chains 1..7 start with pk_mul ----
    pk_fma(c0, a[0][0].h[0], xv0.h[0]);
    f2 c1 = pk_mul(a[1][0].h[0], xv0.h[0]);
    f2 c2 = pk_mul(a[2][0].h[0], xv0.h[0]);
    f2 c3 = pk_mul(a[3][0].h[0], xv0.h[0]);
    f2 c4 = pk_mul(a[4][0].h[0], xv0.h[0]);
    f2 c5 = pk_mul(a[5][0].h[0], xv0.h[0]);
    f2 c6 = pk_mul(a[6][0].h[0], xv0.h[0]);
    f2 c7 = pk_mul(a[7][0].h[0], xv0.h[0]);

    pk_fma(c0, a[0][0].h[1], xv0.h[1]);
    pk_fma(c1, a[1][0].h[1], xv0.h[1]);
    pk_fma(c2, a[2][0].h[1], xv0.h[1]);
    pk_fma(c3, a[3][0].h[1], xv0.h[1]);
    pk_fma(c4, a[4][0].h[1], xv0.h[1]);
    pk_fma(c5, a[5][0].h[1], xv0.h[1]);
    pk_fma(c6, a[6][0].h[1], xv0.h[1]);
    pk_fma(c7, a[7][0].h[1], xv0.h[1]);

    pk_fma(c0, a[0][1].h[0], xv1.h[0]);
    pk_fma(c1, a[1][1].h[0], xv1.h[0]);
    pk_fma(c2, a[2][1].h[0], xv1.h[0]);
    pk_fma(c3, a[3][1].h[0], xv1.h[0]);
    pk_fma(c4, a[4][1].h[0], xv1.h[0]);
    pk_fma(c5, a[5][1].h[0], xv1.h[0]);
    pk_fma(c6, a[6][1].h[0], xv1.h[0]);
    pk_fma(c7, a[7][1].h[0], xv1.h[0]);

    pk_fma(c0, a[0][1].h[1], xv1.h[1]);
    pk_fma(c1, a[1][1].h[1], xv1.h[1]);
    pk_fma(c2, a[2][1].h[1], xv1.h[1]);
    pk_fma(c3, a[3][1].h[1], xv1.h[1]);
    pk_fma(c4, a[4][1].h[1], xv1.h[1]);
    pk_fma(c5, a[5][1].h[1], xv1.h[1]);
    pk_fma(c6, a[6][1].h[1], xv1.h[1]);
    pk_fma(c7, a[7][1].h[1], xv1.h[1]);

    float acc0 = c0.x + c0.y;
    float acc1 = c1.x + c1.y;
    float acc2 = c2.x + c2.y;
    float acc3 = c3.x + c3.y;
    float acc4 = c4.x + c4.y;
    float acc5 = c5.x + c5.y;
    float acc6 = c6.x + c6.y;
    float acc7 = c7.x + c7.y;

    // ---- depth-4, 8-op butterfly over masks {1,2,7,8} ----
    // stage 1 (xor1): self-keeps chosen so each partner holds the SAME row
    float m0 = dpp_add<0xB1>(acc0, acc1);  // row j      (partner acc1 = row j)
    float m2 = dpp_add<0xB1>(acc2, acc3);  // row j^2
    float m5 = dpp_add<0xB1>(acc5, acc4);  // row j^5
    float m7 = dpp_add<0xB1>(acc7, acc6);  // row j^7
    // stage 2 (xor2)
    float w0 = dpp_add<0x4E>(m0, m2);      // row j   over cp bits {0,1}
    float w7 = dpp_add<0x4E>(m7, m5);      // row j^7 over cp bits {0,1}
    // stage 3 (xor7 = row_half_mirror): partner's w7 = row (j^7)^7 = j
    float fv = dpp_add<0x141>(w0, w7);     // row j over cp bits {0,1,2}
    // stage 4 (xor8 = row_ror:8): partner has same j
    float sum = dpp_add<0x128>(fv, fv);    // row j over all 16 parts

    // ---- tail: exp2 -> add -> rcp -> fma(into xf1) -> store ----
    float e = __builtin_amdgcn_exp2f(sum);  // sum pre-scaled by 2*log2(e)
    float xf_new = fmaf(-2.f, __builtin_amdgcn_rcpf(e + 1.f), xf1);
    dst[12 * (r >> 3) + (r & 7)] = xf_new;  // dual write, bit-identical
    xlast = xf_new;

    // raw barrier: drain LDS ops only; vmem prefetches stay in flight
    asm volatile("s_waitcnt lgkmcnt(0)" ::: "memory");
    __builtin_amdgcn_s_barrier();
    asm volatile("" ::: "memory");

    uv = uv_next;   // register renames (free under the 4x unroll)
    xcar = xnew;
  };

#pragma unroll 1
  for (int s = 0; s < NSTEPS; s += 4) {
    step(xs0, xs1, s);
    step(xs1, xs0, s + 1);
    step(xs0, xs1, s + 2);
    step(xs1, xs0, s + 3);
  }
  // pending final term: xlast = x_N, xr0 = xref row N
  {
    float dd = xlast - xr0;
    msef = fmaf(dd, dd, msef);
  }

  // ---- final reduction in f64 (each row counted exactly twice -> /2) ----
  double mse = (double)msef;
#pragma unroll
  for (int off = 1; off < 64; off <<= 1) mse += __shfl_xor(mse, off, 64);
  if ((t & 63) == 0) wsum[t >> 6] = mse;
  __syncthreads();
  if (t == 0) {
    double tot = wsum[0] + wsum[1] + wsum[2] + wsum[3];
    out[0] = (float)(tot / (2.0 * (double)((NSTEPS + 1) * NX)));
  }
}

extern "C" void kernel_launch(void* const* d_in, const int* in_sizes, int n_in,
                              void* d_out, int out_size, void* d_ws, size_t ws_size,
                              hipStream_t stream) {
  const float* x0 = (const float*)d_in[0];
  const float* xref = (const float*)d_in[1];
  const float* useq = (const float*)d_in[2];
  const float* A = (const float*)d_in[3];
  const float* B = (const float*)d_in[4];
  float* out = (float*)d_out;

  nmpc_rollout_kernel<<<dim3(1), dim3(256), 0, stream>>>(x0, xref, useq, A, B, out);
}